// Round 3
// baseline (53.528 us; speedup 1.0000x reference)
//
#include <hip/hip_runtime.h>
#include <math.h>

#define NP 100
#define NPILLAR 24000
#define OUT_CH 64
#define NTOTAL 2400000.0            // bs*V*P
#define VXc 0.2f
#define VYc 0.2f
#define XOFF 0.1f
#define YOFF (-39.9f)
#define BN_EPS 1e-3
#define SB 1024                     // stats blocks (4096 waves = 4/SIMD)

typedef __attribute__((ext_vector_type(8))) short bf16x8;
typedef __attribute__((ext_vector_type(16))) float f32x16;
typedef __attribute__((ext_vector_type(4))) unsigned int uint4v;

__device__ __forceinline__ unsigned int f2bf(float x) {
    unsigned int b = __builtin_bit_cast(unsigned int, x);
    b += 0x7FFFu + ((b >> 16) & 1u);   // RNE
    return b >> 16;                    // bf16 in low 16 bits
}

__device__ __forceinline__ void build_f(const float4 p, float mx, float my, float mz,
                                        float cx, float cy, float* f) {
    f[0] = p.x; f[1] = p.y; f[2] = p.z; f[3] = p.w;
    f[4] = p.x - mx; f[5] = p.y - my; f[6] = p.z - mz;
    f[7] = p.x - cx; f[8] = p.y - cy;
}

// ---------------- Pass 1: global moments (9 first + 45 second) --------------
__global__ __launch_bounds__(256) void pfn_stats(
    const float4* __restrict__ feat, const int* __restrict__ npts,
    const int* __restrict__ coors, float* __restrict__ part)
{
    const int tid = threadIdx.x;
    const int lane = tid & 63;
    const int wv = tid >> 6;
    const int gw = blockIdx.x * 4 + wv;
    const int nw = SB * 4;

    float s[54];
#pragma unroll
    for (int i = 0; i < 54; ++i) s[i] = 0.f;

    for (int pv = gw; pv < NPILLAR; pv += nw) {
        const float4* fp = feat + (size_t)pv * NP;
        float4 p0 = fp[lane];
        float4 p1 = (lane + 64 < NP) ? fp[lane + 64] : make_float4(0.f, 0.f, 0.f, 0.f);

        float sx = p0.x + p1.x, sy = p0.y + p1.y, sz = p0.z + p1.z;
#pragma unroll
        for (int off = 32; off; off >>= 1) {
            sx += __shfl_xor(sx, off);
            sy += __shfl_xor(sy, off);
            sz += __shfl_xor(sz, off);
        }
        int np_ = npts[pv];
        if (np_ > NP) np_ = NP;
        float inv = 1.f / fmaxf((float)np_, 1.f);
        float mx = sx * inv, my = sy * inv, mz = sz * inv;
        float cx = (float)coors[pv * 4 + 2] * VXc + XOFF;
        float cy = (float)coors[pv * 4 + 1] * VYc + YOFF;

        float f[9];
        if (lane < np_) {
            build_f(p0, mx, my, mz, cx, cy, f);
            int k = 9;
#pragma unroll
            for (int i = 0; i < 9; ++i) {
                s[i] += f[i];
#pragma unroll
                for (int j = i; j < 9; ++j) s[k++] = fmaf(f[i], f[j], s[k]);
            }
        }
        if (lane + 64 < np_) {
            build_f(p1, mx, my, mz, cx, cy, f);
            int k = 9;
#pragma unroll
            for (int i = 0; i < 9; ++i) {
                s[i] += f[i];
#pragma unroll
                for (int j = i; j < 9; ++j) s[k++] = fmaf(f[i], f[j], s[k]);
            }
        }
    }

#pragma unroll
    for (int i = 0; i < 54; ++i) {
#pragma unroll
        for (int off = 32; off; off >>= 1) s[i] += __shfl_xor(s[i], off);
    }

    __shared__ float red[4][54];
    if (lane == 0) {
#pragma unroll
        for (int i = 0; i < 54; ++i) red[wv][i] = s[i];
    }
    __syncthreads();
    if (tid < 64) {
        float v = 0.f;
        if (tid < 54)
            v = red[0][tid] + red[1][tid] + red[2][tid] + red[3][tid];
        part[blockIdx.x * 64 + tid] = v;
    }
}

// ---------------- Pass 2: reduce partials -> per-channel scale/shift --------
__global__ __launch_bounds__(1024) void pfn_finalize(
    const float* __restrict__ part, const float* __restrict__ W,
    const float* __restrict__ gamma, const float* __restrict__ beta,
    float* __restrict__ scsh)
{
    __shared__ double red[16][64];
    __shared__ double dm[64];
    const int t = threadIdx.x;
    const int m = t & 63;
    const int chunk = t >> 6;

    double s = 0.0;
#pragma unroll 8
    for (int b = chunk * 64; b < chunk * 64 + 64; ++b)
        s += (double)part[b * 64 + m];
    red[chunk][m] = s;
    __syncthreads();
    if (t < 64) {
        double tot = 0.0;
#pragma unroll
        for (int c = 0; c < 16; ++c) tot += red[c][t];
        dm[t] = tot;
    }
    __syncthreads();
    if (t < 64) {
        double w[9];
#pragma unroll
        for (int i = 0; i < 9; ++i) w[i] = (double)W[i * OUT_CH + t];
        double mean = 0.0;
#pragma unroll
        for (int i = 0; i < 9; ++i) mean += dm[i] * w[i];
        mean /= NTOTAL;
        double ex2 = 0.0;
        int k = 9;
#pragma unroll
        for (int i = 0; i < 9; ++i) {
#pragma unroll
            for (int j = i; j < 9; ++j) {
                double c = dm[k++];
                ex2 += (i == j ? 1.0 : 2.0) * c * w[i] * w[j];
            }
        }
        ex2 /= NTOTAL;
        double var = ex2 - mean * mean;
        double scale = (double)gamma[t] / sqrt(var + BN_EPS);
        double shift = (double)beta[t] - mean * scale;
        scsh[t] = (float)scale;
        scsh[OUT_CH + t] = (float)shift;
    }
}

// ---------------- Pass 3: MFMA x, per-pillar max/min, direct output ---------
// One wave per pillar; A-fragments via __shfl from registers (no LDS).
__global__ __launch_bounds__(256) void pfn_out(
    const float4* __restrict__ feat, const int* __restrict__ npts,
    const int* __restrict__ coors, const float* __restrict__ W,
    const float* __restrict__ scsh, float* __restrict__ out)
{
    const int tid = threadIdx.x;
    const int lane = tid & 63;
    const int wv = tid >> 6;
    const int pv = blockIdx.x * 4 + wv;

    // B fragments: lane holds B[k=(lane>>5)*8+i][col=(lane&31)(+32)]
    const int col = lane & 31;
    const int kbase = (lane >> 5) * 8;
    bf16x8 bfr0, bfr1;
#pragma unroll
    for (int i = 0; i < 8; ++i) {
        int k = kbase + i;
        float w0 = (k < 9) ? W[k * OUT_CH + col] : 0.f;
        float w1 = (k < 9) ? W[k * OUT_CH + 32 + col] : 0.f;
        bfr0[i] = (short)f2bf(w0);
        bfr1[i] = (short)f2bf(w1);
    }

    const float4* fp = feat + (size_t)pv * NP;
    float4 p0 = fp[lane];
    float4 p1 = (lane + 64 < NP) ? fp[lane + 64] : make_float4(0.f, 0.f, 0.f, 0.f);

    float sx = p0.x + p1.x, sy = p0.y + p1.y, sz = p0.z + p1.z;
#pragma unroll
    for (int off = 32; off; off >>= 1) {
        sx += __shfl_xor(sx, off);
        sy += __shfl_xor(sy, off);
        sz += __shfl_xor(sz, off);
    }
    int np_ = npts[pv];
    if (np_ > NP) np_ = NP;
    float inv = 1.f / fmaxf((float)np_, 1.f);
    float mx = sx * inv, my = sy * inv, mz = sz * inv;
    float cx = (float)coors[pv * 4 + 2] * VXc + XOFF;
    float cy = (float)coors[pv * 4 + 1] * VYc + YOFF;

    // pack 9 bf16 features into 5 u32 words per loaded point (invalid -> 0)
    unsigned int A[5], B[5];
    {
        float f[9];
        if (lane < np_) {
            build_f(p0, mx, my, mz, cx, cy, f);
            A[0] = f2bf(f[0]) | (f2bf(f[1]) << 16);
            A[1] = f2bf(f[2]) | (f2bf(f[3]) << 16);
            A[2] = f2bf(f[4]) | (f2bf(f[5]) << 16);
            A[3] = f2bf(f[6]) | (f2bf(f[7]) << 16);
            A[4] = f2bf(f[8]);
        } else {
#pragma unroll
            for (int i = 0; i < 5; ++i) A[i] = 0u;
        }
        if (lane + 64 < np_) {
            build_f(p1, mx, my, mz, cx, cy, f);
            B[0] = f2bf(f[0]) | (f2bf(f[1]) << 16);
            B[1] = f2bf(f[2]) | (f2bf(f[3]) << 16);
            B[2] = f2bf(f[4]) | (f2bf(f[5]) << 16);
            B[3] = f2bf(f[6]) | (f2bf(f[7]) << 16);
            B[4] = f2bf(f[8]);
        } else {
#pragma unroll
            for (int i = 0; i < 5; ++i) B[i] = 0u;
        }
    }

    f32x16 cz;
#pragma unroll
    for (int i = 0; i < 16; ++i) cz[i] = 0.f;

    float xmx0 = -INFINITY, xmx1 = -INFINITY;
    float xmn0 = INFINITY, xmn1 = INFINITY;
    const bool lo = (lane < 32);
    const int nmt = (np_ + 31) >> 5;

    for (int mt = 0; mt < nmt; ++mt) {
        const int src = ((mt & 1) << 5) + col;   // lane holding row mt*32+col
        unsigned int w0, w1, w2, w3, w4;
        if (mt < 2) {
            w0 = __shfl((int)A[0], src); w1 = __shfl((int)A[1], src);
            w2 = __shfl((int)A[2], src); w3 = __shfl((int)A[3], src);
            w4 = __shfl((int)A[4], src);
        } else {
            w0 = __shfl((int)B[0], src); w1 = __shfl((int)B[1], src);
            w2 = __shfl((int)B[2], src); w3 = __shfl((int)B[3], src);
            w4 = __shfl((int)B[4], src);
        }
        uint4v av = {lo ? w0 : w4, lo ? w1 : 0u, lo ? w2 : 0u, lo ? w3 : 0u};
        bf16x8 afr = __builtin_bit_cast(bf16x8, av);

        f32x16 c0 = __builtin_amdgcn_mfma_f32_32x32x16_bf16(afr, bfr0, cz, 0, 0, 0);
        f32x16 c1 = __builtin_amdgcn_mfma_f32_32x32x16_bf16(afr, bfr1, cz, 0, 0, 0);
#pragma unroll
        for (int r = 0; r < 16; r += 2) {
            xmx0 = fmaxf(xmx0, fmaxf(c0[r], c0[r + 1]));
            xmn0 = fminf(xmn0, fminf(c0[r], c0[r + 1]));
            xmx1 = fmaxf(xmx1, fmaxf(c1[r], c1[r + 1]));
            xmn1 = fminf(xmn1, fminf(c1[r], c1[r + 1]));
        }
    }

    // padded positions (np_ <= 99 < NP always) contribute x = 0
    if (np_ < NP) {
        xmx0 = fmaxf(xmx0, 0.f); xmx1 = fmaxf(xmx1, 0.f);
        xmn0 = fminf(xmn0, 0.f); xmn1 = fminf(xmn1, 0.f);
    }

    xmx0 = fmaxf(xmx0, __shfl_xor(xmx0, 32));
    xmx1 = fmaxf(xmx1, __shfl_xor(xmx1, 32));
    xmn0 = fminf(xmn0, __shfl_xor(xmn0, 32));
    xmn1 = fminf(xmn1, __shfl_xor(xmn1, 32));

    // lane -> channel: lanes 0-31 = c0 cols 0-31, lanes 32-63 = c1 cols 32-63
    float xmx = lo ? xmx0 : xmx1;
    float xmn = lo ? xmn0 : xmn1;
    float scale = scsh[lane];
    float shift = scsh[OUT_CH + lane];
    out[(size_t)pv * OUT_CH + lane] =
        fmaxf(fmaf(scale, (scale >= 0.f) ? xmx : xmn, shift), 0.f);
}

extern "C" void kernel_launch(void* const* d_in, const int* in_sizes, int n_in,
                              void* d_out, int out_size, void* d_ws, size_t ws_size,
                              hipStream_t stream) {
    const float4* feat = (const float4*)d_in[0];
    const int* npts    = (const int*)d_in[1];
    const int* coors   = (const int*)d_in[2];
    const float* W     = (const float*)d_in[3];
    const float* gamma = (const float*)d_in[4];
    const float* beta  = (const float*)d_in[5];

    float* part = (float*)d_ws;                 // SB*64 f32 partials
    float* scsh = part + SB * 64;               // 128 f32

    pfn_stats<<<SB, 256, 0, stream>>>(feat, npts, coors, part);
    pfn_finalize<<<1, 1024, 0, stream>>>(part, W, gamma, beta, scsh);
    pfn_out<<<NPILLAR / 4, 256, 0, stream>>>(feat, npts, coors, W, scsh,
                                             (float*)d_out);
}